// Round 8
// baseline (167.785 us; speedup 1.0000x reference)
//
#include <hip/hip_runtime.h>
#include <cstdint>
#include <cstddef>

#define S_LEN 3072
#define E_DIM 1024
#define NH 16
#define NKV 8
#define HD 64
#define NQKV 2048
#define SEG 1024

typedef __attribute__((ext_vector_type(8))) short bf16x8;
typedef __attribute__((ext_vector_type(4))) float f32x4;
typedef __attribute__((ext_vector_type(4))) float ff4;
typedef __attribute__((ext_vector_type(4))) short s16x4;
typedef unsigned short u16;

// 0.125 * log2(e): folded into Q so attention uses exp2 directly
#define QSCALE 0.1803368801111204f

__device__ __forceinline__ u16 f2bf(float f) {
    unsigned u = __float_as_uint(f);
    u += 0x7fffu + ((u >> 16) & 1u);
    return (u16)(u >> 16);
}

__device__ __forceinline__ void gld16(const void* g, u16* l) {
    __builtin_amdgcn_global_load_lds(
        (const __attribute__((address_space(1))) unsigned*)g,
        (__attribute__((address_space(3))) unsigned*)l, 16, 0, 0);
}

// ---------------- cast f32 -> bf16 for x, qkv_w, proj_w ----------------
__global__ __launch_bounds__(256) void k_cast(
    const float* __restrict__ x, const float* __restrict__ w, const float* __restrict__ pw,
    u16* __restrict__ xb, u16* __restrict__ wb, u16* __restrict__ pwb)
{
    const int n1 = (S_LEN * E_DIM) / 4, n2 = (NQKV * E_DIM) / 4, n3 = (E_DIM * E_DIM) / 4;
    const int total = n1 + n2 + n3;
    for (int i = blockIdx.x * 256 + threadIdx.x; i < total; i += gridDim.x * 256) {
        const float* s; u16* d; int j;
        if (i < n1)           { s = x;  d = xb;  j = i; }
        else if (i < n1 + n2) { s = w;  d = wb;  j = i - n1; }
        else                  { s = pw; d = pwb; j = i - n1 - n2; }
        ff4 v = *(const ff4*)&s[(size_t)j * 4];
        unsigned lo = (unsigned)f2bf(v.x) | ((unsigned)f2bf(v.y) << 16);
        unsigned hi = (unsigned)f2bf(v.z) | ((unsigned)f2bf(v.w) << 16);
        uint2 pk; pk.x = lo; pk.y = hi;
        *(uint2*)&d[(size_t)j * 4] = pk;
    }
}

// ---------------- QKV GEMM (64x128, 768 blocks) + bias + RoPE + scatter ----------------
// grid (48, 16), 256 thr. BK=64. wave: 32(M) x 64(N).
__global__ __launch_bounds__(256) void k_qkv(
    const u16* __restrict__ xb, const u16* __restrict__ wb,
    const float* __restrict__ bias, const float* __restrict__ rc, const float* __restrict__ rs,
    u16* __restrict__ qb, u16* __restrict__ kb, u16* __restrict__ vb)
{
    __shared__ u16 smA[64 * 64];
    __shared__ u16 smB[128 * 64];
    const int tid = threadIdx.x;
    const int wv = tid >> 6, ln = tid & 63;
    const int s0 = blockIdx.x * 64;
    const int o0 = blockIdx.y * 128;
    const int wr = wv >> 1, wc = wv & 1;
    const int col = ln & 15, lg = ln >> 4;

    f32x4 acc[2][4] = {};

    for (int kt = 0; kt < E_DIM / 64; ++kt) {
        const int k0 = kt * 64;
        #pragma unroll
        for (int i = 0; i < 2; ++i) {       // A: 64x64 = 512 chunks
            int c = i * 256 + tid;
            int row = c >> 3, sl = c & 7;
            int gs = (sl ^ (row & 7)) << 3;
            gld16(&xb[(size_t)(s0 + row) * E_DIM + k0 + gs], &smA[(i * 256 + wv * 64) * 8]);
        }
        #pragma unroll
        for (int i = 0; i < 4; ++i) {       // B: 128x64 = 1024 chunks
            int c = i * 256 + tid;
            int row = c >> 3, sl = c & 7;
            int gs = (sl ^ (row & 7)) << 3;
            gld16(&wb[(size_t)(o0 + row) * E_DIM + k0 + gs], &smB[(i * 256 + wv * 64) * 8]);
        }
        __syncthreads();
        #pragma unroll
        for (int ks = 0; ks < 2; ++ks) {
            bf16x8 a[2], b[4];
            #pragma unroll
            for (int mi = 0; mi < 2; ++mi) {
                int row = wr * 32 + mi * 16 + col;
                int sl = (ks * 4 + lg) ^ (row & 7);
                a[mi] = *(const bf16x8*)&smA[row * 64 + sl * 8];
            }
            #pragma unroll
            for (int ni = 0; ni < 4; ++ni) {
                int row = wc * 64 + ni * 16 + col;
                int sl = (ks * 4 + lg) ^ (row & 7);
                b[ni] = *(const bf16x8*)&smB[row * 64 + sl * 8];
            }
            #pragma unroll
            for (int mi = 0; mi < 2; ++mi)
                #pragma unroll
                for (int ni = 0; ni < 4; ++ni)
                    acc[mi][ni] = __builtin_amdgcn_mfma_f32_16x16x32_bf16(a[mi], b[ni], acc[mi][ni], 0, 0, 0);
        }
        __syncthreads();
    }

    const int ocol0 = o0 + wc * 64;      // wave covers exactly one head
    const int head = ocol0 >> 6;
    #pragma unroll
    for (int ni = 0; ni < 4; ++ni) {
        float bv = bias[ocol0 + ni * 16 + col];
        #pragma unroll
        for (int mi = 0; mi < 2; ++mi)
            #pragma unroll
            for (int r = 0; r < 4; ++r)
                acc[mi][ni][r] += bv;
    }
    if (head < NH + NKV) {   // RoPE on q and k heads
        #pragma unroll
        for (int mi = 0; mi < 2; ++mi)
            #pragma unroll
            for (int r = 0; r < 4; ++r) {
                int s = s0 + wr * 32 + mi * 16 + lg * 4 + r;
                #pragma unroll
                for (int ni = 0; ni < 2; ++ni) {
                    int d2 = ni * 16 + col;
                    float c = rc[s * 32 + d2], sn = rs[s * 32 + d2];
                    float t1 = acc[mi][ni][r], t2 = acc[mi][ni + 2][r];
                    acc[mi][ni][r]     = t1 * c - t2 * sn;
                    acc[mi][ni + 2][r] = t1 * sn + t2 * c;
                }
            }
    }
    if (head < NH) {         // fold 0.125*log2e into Q (attention uses exp2)
        #pragma unroll
        for (int mi = 0; mi < 2; ++mi)
            #pragma unroll
            for (int ni = 0; ni < 4; ++ni)
                #pragma unroll
                for (int r = 0; r < 4; ++r)
                    acc[mi][ni][r] *= QSCALE;
    }
    if (head < NH + NKV) {   // q/k: [h][s][d]
        u16* dst; int hh;
        if (head < NH) { dst = qb; hh = head; } else { dst = kb; hh = head - NH; }
        #pragma unroll
        for (int mi = 0; mi < 2; ++mi)
            #pragma unroll
            for (int r = 0; r < 4; ++r) {
                int s = s0 + wr * 32 + mi * 16 + lg * 4 + r;
                #pragma unroll
                for (int ni = 0; ni < 4; ++ni)
                    dst[((size_t)hh * S_LEN + s) * HD + ni * 16 + col] = f2bf(acc[mi][ni][r]);
            }
    } else {                 // v: [h][d][s] transposed, 8B packed stores
        int hh = head - NH - NKV;
        #pragma unroll
        for (int mi = 0; mi < 2; ++mi) {
            int sb = s0 + wr * 32 + mi * 16 + lg * 4;
            #pragma unroll
            for (int ni = 0; ni < 4; ++ni) {
                int d = ni * 16 + col;
                s16x4 pk;
                #pragma unroll
                for (int r = 0; r < 4; ++r) pk[r] = (short)f2bf(acc[mi][ni][r]);
                *(s16x4*)&vb[((size_t)hh * HD + d) * S_LEN + sb] = pk;
            }
        }
    }
}

// ---------------- attention: K staged (dbuf), V direct-to-register (T14 async split) ----
// grid (48, 16 heads), 256 thr. Block: 64 q-rows; wave: 16 q-rows. KV tile 64.
// V loads issue at tile top (registers, L2-served), consumed in PV ~600cy later.
__global__ __launch_bounds__(256) void k_attn(
    const u16* __restrict__ qb, const u16* __restrict__ kb, const u16* __restrict__ vb,
    u16* __restrict__ cb)
{
    __shared__ u16 smK[2][64 * 64];
    __shared__ u16 smP[4 * 16 * 64];     // per-wave P
    const int tid = threadIdx.x;
    const int wv = tid >> 6, ln = tid & 63;
    const int h = blockIdx.y, kvh = h >> 1;
    const int s0 = blockIdx.x * 64;
    const int seg0 = s0 & ~(SEG - 1);
    const int col = ln & 15, lg = ln >> 4;

    bf16x8 qf[2];
    #pragma unroll
    for (int ks = 0; ks < 2; ++ks)
        qf[ks] = *(const bf16x8*)&qb[((size_t)h * S_LEN + s0 + wv * 16 + col) * HD + ks * 32 + lg * 8];

    f32x4 oacc[4] = {};
    float lsum[4] = {0.f, 0.f, 0.f, 0.f};
    u16* myP = &smP[wv * 16 * 64];

    const u16* Kseg = kb + ((size_t)kvh * S_LEN + seg0) * HD;   // [t][d]
    const u16* Vseg = vb + (size_t)kvh * HD * S_LEN + seg0;     // [d][s]

    auto stageK = [&](int b, int kt) {
        #pragma unroll
        for (int i = 0; i < 2; ++i) {
            int c = i * 256 + tid; int row = c >> 3, sl = c & 7; int gs = (sl ^ (row & 7)) << 3;
            gld16(&Kseg[(size_t)(kt * 64 + row) * HD + gs], &smK[b][(i * 256 + wv * 64) * 8]);
        }
    };

    stageK(0, 0);
    __syncthreads();

    for (int kt = 0; kt < SEG / 64; ++kt) {
        const int cur = kt & 1;

        // issue V fragment loads early: per 4-lane group a contiguous 64B of row d
        bf16x8 vf[2][4];
        #pragma unroll
        for (int ks = 0; ks < 2; ++ks)
            #pragma unroll
            for (int ni = 0; ni < 4; ++ni)
                vf[ks][ni] = *(const bf16x8*)&Vseg[(size_t)(ni * 16 + col) * S_LEN + kt * 64 + ks * 32 + lg * 8];

        if (kt + 1 < SEG / 64) stageK(cur ^ 1, kt + 1);   // prefetch next K tile (no wait)

        // QK^T from staged K
        f32x4 sacc[4] = {};
        #pragma unroll
        for (int ks = 0; ks < 2; ++ks) {
            bf16x8 kf[4];
            #pragma unroll
            for (int ni = 0; ni < 4; ++ni) {
                int row = ni * 16 + col;
                int sl = (ks * 4 + lg) ^ (row & 7);
                kf[ni] = *(const bf16x8*)&smK[cur][row * 64 + sl * 8];
            }
            #pragma unroll
            for (int ni = 0; ni < 4; ++ni)
                sacc[ni] = __builtin_amdgcn_mfma_f32_16x16x32_bf16(qf[ks], kf[ni], sacc[ni], 0, 0, 0);
        }

        // p = exp2(s); per-lane partial row sums (deferred reduce)
        #pragma unroll
        for (int ni = 0; ni < 4; ++ni)
            #pragma unroll
            for (int r = 0; r < 4; ++r) {
                float p = __builtin_amdgcn_exp2f(sacc[ni][r]);
                sacc[ni][r] = p;
                lsum[r] += p;
            }

        // P -> wave-private LDS (swizzled 128B rows); same-wave, no barrier
        #pragma unroll
        for (int ni = 0; ni < 4; ++ni)
            #pragma unroll
            for (int r = 0; r < 4; ++r) {
                int row = lg * 4 + r;
                int t = ni * 16 + col;
                int b = (t >> 3) ^ (row & 7);
                myP[row * 64 + b * 8 + (t & 7)] = f2bf(sacc[ni][r]);
            }

        // PV: P from LDS, V from registers
        #pragma unroll
        for (int ks = 0; ks < 2; ++ks) {
            bf16x8 pf;
            {
                int row = col;
                int sl = (ks * 4 + lg) ^ (row & 7);
                pf = *(const bf16x8*)&myP[row * 64 + sl * 8];
            }
            #pragma unroll
            for (int ni = 0; ni < 4; ++ni)
                oacc[ni] = __builtin_amdgcn_mfma_f32_16x16x32_bf16(pf, vf[ks][ni], oacc[ni], 0, 0, 0);
        }

        __syncthreads();   // drains K prefetch DMA + releases cur for overwrite
    }

    // deferred row-sum reduce (within 16-lane col groups)
    #pragma unroll
    for (int r = 0; r < 4; ++r) {
        float v = lsum[r];
        v += __shfl_xor(v, 1); v += __shfl_xor(v, 2);
        v += __shfl_xor(v, 4); v += __shfl_xor(v, 8);
        lsum[r] = v;
    }

    #pragma unroll
    for (int r = 0; r < 4; ++r) {
        int s = s0 + wv * 16 + lg * 4 + r;
        float inv = 1.f / lsum[r];
        #pragma unroll
        for (int ni = 0; ni < 4; ++ni) {
            int d = ni * 16 + col;
            cb[(size_t)s * E_DIM + h * HD + d] = f2bf(oacc[ni][r] * inv);
        }
    }
}

// ---------------- output projection (64x64, 768 blocks, f32 out) ----------------
// grid (48, 16), 256 thr. wave 32x32.
__global__ __launch_bounds__(256) void k_proj(
    const u16* __restrict__ cb, const u16* __restrict__ pwb,
    const float* __restrict__ bias, float* __restrict__ out)
{
    __shared__ u16 smA[64 * 64];
    __shared__ u16 smB[64 * 64];
    const int tid = threadIdx.x;
    const int wv = tid >> 6, ln = tid & 63;
    const int s0 = blockIdx.x * 64, o0 = blockIdx.y * 64;
    const int wr = wv >> 1, wc = wv & 1;
    const int col = ln & 15, lg = ln >> 4;

    f32x4 acc[2][2] = {};

    for (int kt = 0; kt < E_DIM / 64; ++kt) {
        const int k0 = kt * 64;
        #pragma unroll
        for (int i = 0; i < 2; ++i) {
            int c = i * 256 + tid; int row = c >> 3, sl = c & 7; int gs = (sl ^ (row & 7)) << 3;
            gld16(&cb[(size_t)(s0 + row) * E_DIM + k0 + gs], &smA[(i * 256 + wv * 64) * 8]);
        }
        #pragma unroll
        for (int i = 0; i < 2; ++i) {
            int c = i * 256 + tid; int row = c >> 3, sl = c & 7; int gs = (sl ^ (row & 7)) << 3;
            gld16(&pwb[(size_t)(o0 + row) * E_DIM + k0 + gs], &smB[(i * 256 + wv * 64) * 8]);
        }
        __syncthreads();
        #pragma unroll
        for (int ks = 0; ks < 2; ++ks) {
            bf16x8 a[2], b[2];
            #pragma unroll
            for (int mi = 0; mi < 2; ++mi) {
                int row = wr * 32 + mi * 16 + col;
                int sl = (ks * 4 + lg) ^ (row & 7);
                a[mi] = *(const bf16x8*)&smA[row * 64 + sl * 8];
            }
            #pragma unroll
            for (int ni = 0; ni < 2; ++ni) {
                int row = wc * 32 + ni * 16 + col;
                int sl = (ks * 4 + lg) ^ (row & 7);
                b[ni] = *(const bf16x8*)&smB[row * 64 + sl * 8];
            }
            #pragma unroll
            for (int mi = 0; mi < 2; ++mi)
                #pragma unroll
                for (int ni = 0; ni < 2; ++ni)
                    acc[mi][ni] = __builtin_amdgcn_mfma_f32_16x16x32_bf16(a[mi], b[ni], acc[mi][ni], 0, 0, 0);
        }
        __syncthreads();
    }

    #pragma unroll
    for (int mi = 0; mi < 2; ++mi)
        #pragma unroll
        for (int r = 0; r < 4; ++r) {
            int s = s0 + wr * 32 + mi * 16 + lg * 4 + r;
            #pragma unroll
            for (int ni = 0; ni < 2; ++ni) {
                int o = o0 + wc * 32 + ni * 16 + col;
                out[(size_t)s * E_DIM + o] = acc[mi][ni][r] + bias[o];
            }
        }
}

extern "C" void kernel_launch(void* const* d_in, const int* in_sizes, int n_in,
                              void* d_out, int out_size, void* d_ws, size_t ws_size,
                              hipStream_t stream) {
    const float* x      = (const float*)d_in[0];
    const float* rc     = (const float*)d_in[2];
    const float* rs     = (const float*)d_in[3];
    const float* qkv_w  = (const float*)d_in[4];
    const float* qkv_b  = (const float*)d_in[5];
    const float* proj_w = (const float*)d_in[6];
    const float* proj_b = (const float*)d_in[7];
    float* out = (float*)d_out;

    u16* ws  = (u16*)d_ws;
    u16* xb  = ws;                                  // 3072*1024
    u16* wb  = xb  + (size_t)S_LEN * E_DIM;         // 2048*1024
    u16* pwb = wb  + (size_t)NQKV * E_DIM;          // 1024*1024
    u16* qb  = pwb + (size_t)E_DIM * E_DIM;         // 16*3072*64
    u16* kb  = qb  + (size_t)NH * S_LEN * HD;       // 8*3072*64
    u16* vb  = kb  + (size_t)NKV * S_LEN * HD;      // 8*64*3072 (transposed)
    u16* cb  = vb  + (size_t)NKV * S_LEN * HD;      // 3072*1024

    k_cast<<<1536, 256, 0, stream>>>(x, qkv_w, proj_w, xb, wb, pwb);
    k_qkv <<<dim3(48, 16), 256, 0, stream>>>(xb, wb, qkv_b, rc, rs, qb, kb, vb);
    k_attn<<<dim3(48, 16), 256, 0, stream>>>(qb, kb, vb, cb);
    k_proj<<<dim3(48, 16), 256, 0, stream>>>(cb, pwb, proj_b, out);
}

// Round 12
// 146.390 us; speedup vs baseline: 1.1462x; 1.1462x over previous
//
#include <hip/hip_runtime.h>
#include <cstdint>
#include <cstddef>

#define S_LEN 3072
#define E_DIM 1024
#define NH 16
#define NKV 8
#define HD 64
#define NQKV 2048
#define SEG 1024

typedef __attribute__((ext_vector_type(8))) short bf16x8;
typedef __attribute__((ext_vector_type(4))) float f32x4;
typedef __attribute__((ext_vector_type(4))) float ff4;
typedef __attribute__((ext_vector_type(4))) short s16x4;
typedef unsigned short u16;

// 0.125 * log2(e): folded into Q so attention uses exp2 directly
#define QSCALE 0.1803368801111204f

__device__ __forceinline__ u16 f2bf(float f) {
    unsigned u = __float_as_uint(f);
    u += 0x7fffu + ((u >> 16) & 1u);
    return (u16)(u >> 16);
}

__device__ __forceinline__ void gld16(const void* g, u16* l) {
    __builtin_amdgcn_global_load_lds(
        (const __attribute__((address_space(1))) unsigned*)g,
        (__attribute__((address_space(3))) unsigned*)l, 16, 0, 0);
}

// ---------------- cast f32 -> bf16 for x, qkv_w, proj_w ----------------
__global__ __launch_bounds__(256) void k_cast(
    const float* __restrict__ x, const float* __restrict__ w, const float* __restrict__ pw,
    u16* __restrict__ xb, u16* __restrict__ wb, u16* __restrict__ pwb)
{
    const int n1 = (S_LEN * E_DIM) / 4, n2 = (NQKV * E_DIM) / 4, n3 = (E_DIM * E_DIM) / 4;
    const int total = n1 + n2 + n3;
    for (int i = blockIdx.x * 256 + threadIdx.x; i < total; i += gridDim.x * 256) {
        const float* s; u16* d; int j;
        if (i < n1)           { s = x;  d = xb;  j = i; }
        else if (i < n1 + n2) { s = w;  d = wb;  j = i - n1; }
        else                  { s = pw; d = pwb; j = i - n1 - n2; }
        ff4 v = *(const ff4*)&s[(size_t)j * 4];
        unsigned lo = (unsigned)f2bf(v.x) | ((unsigned)f2bf(v.y) << 16);
        unsigned hi = (unsigned)f2bf(v.z) | ((unsigned)f2bf(v.w) << 16);
        uint2 pk; pk.x = lo; pk.y = hi;
        *(uint2*)&d[(size_t)j * 4] = pk;
    }
}

// ---------------- QKV GEMM (64x128 tile, BK=128) + bias + RoPE + scatter ----------------
// grid (48, 16), 256 thr. wave: 32(M) x 64(N). 8 K-iterations, 16 barriers.
__global__ __launch_bounds__(256) void k_qkv(
    const u16* __restrict__ xb, const u16* __restrict__ wb,
    const float* __restrict__ bias, const float* __restrict__ rc, const float* __restrict__ rs,
    u16* __restrict__ qb, u16* __restrict__ kb, u16* __restrict__ vb)
{
    __shared__ u16 smA[64 * 128];     // 16KB, rows of 256B (16 slots)
    __shared__ u16 smB[128 * 128];    // 32KB
    const int tid = threadIdx.x;
    const int wv = tid >> 6, ln = tid & 63;
    const int s0 = blockIdx.x * 64;
    const int o0 = blockIdx.y * 128;
    const int wr = wv >> 1, wc = wv & 1;
    const int col = ln & 15, lg = ln >> 4;

    f32x4 acc[2][4] = {};

    for (int kt = 0; kt < E_DIM / 128; ++kt) {
        const int k0 = kt * 128;
        #pragma unroll
        for (int i = 0; i < 4; ++i) {       // A: 64x128 = 1024 16B-chunks
            int c = i * 256 + tid;
            int row = c >> 4, sl = c & 15;
            int gs = (sl ^ (row & 7)) << 3;
            gld16(&xb[(size_t)(s0 + row) * E_DIM + k0 + gs], &smA[(i * 256 + wv * 64) * 8]);
        }
        #pragma unroll
        for (int i = 0; i < 8; ++i) {       // B: 128x128 = 2048 chunks
            int c = i * 256 + tid;
            int row = c >> 4, sl = c & 15;
            int gs = (sl ^ (row & 7)) << 3;
            gld16(&wb[(size_t)(o0 + row) * E_DIM + k0 + gs], &smB[(i * 256 + wv * 64) * 8]);
        }
        __syncthreads();
        #pragma unroll
        for (int ks = 0; ks < 4; ++ks) {
            bf16x8 a[2], b[4];
            #pragma unroll
            for (int mi = 0; mi < 2; ++mi) {
                int row = wr * 32 + mi * 16 + col;
                int sl = (ks * 4 + lg) ^ (row & 7);
                a[mi] = *(const bf16x8*)&smA[row * 128 + sl * 8];
            }
            #pragma unroll
            for (int ni = 0; ni < 4; ++ni) {
                int row = wc * 64 + ni * 16 + col;
                int sl = (ks * 4 + lg) ^ (row & 7);
                b[ni] = *(const bf16x8*)&smB[row * 128 + sl * 8];
            }
            #pragma unroll
            for (int mi = 0; mi < 2; ++mi)
                #pragma unroll
                for (int ni = 0; ni < 4; ++ni)
                    acc[mi][ni] = __builtin_amdgcn_mfma_f32_16x16x32_bf16(a[mi], b[ni], acc[mi][ni], 0, 0, 0);
        }
        __syncthreads();
    }

    const int ocol0 = o0 + wc * 64;      // wave covers exactly one head
    const int head = ocol0 >> 6;
    #pragma unroll
    for (int ni = 0; ni < 4; ++ni) {
        float bv = bias[ocol0 + ni * 16 + col];
        #pragma unroll
        for (int mi = 0; mi < 2; ++mi)
            #pragma unroll
            for (int r = 0; r < 4; ++r)
                acc[mi][ni][r] += bv;
    }
    if (head < NH + NKV) {   // RoPE on q and k heads
        #pragma unroll
        for (int mi = 0; mi < 2; ++mi)
            #pragma unroll
            for (int r = 0; r < 4; ++r) {
                int s = s0 + wr * 32 + mi * 16 + lg * 4 + r;
                #pragma unroll
                for (int ni = 0; ni < 2; ++ni) {
                    int d2 = ni * 16 + col;
                    float c = rc[s * 32 + d2], sn = rs[s * 32 + d2];
                    float t1 = acc[mi][ni][r], t2 = acc[mi][ni + 2][r];
                    acc[mi][ni][r]     = t1 * c - t2 * sn;
                    acc[mi][ni + 2][r] = t1 * sn + t2 * c;
                }
            }
    }
    if (head < NH) {         // fold 0.125*log2e into Q (attention uses exp2)
        #pragma unroll
        for (int mi = 0; mi < 2; ++mi)
            #pragma unroll
            for (int ni = 0; ni < 4; ++ni)
                #pragma unroll
                for (int r = 0; r < 4; ++r)
                    acc[mi][ni][r] *= QSCALE;
    }
    if (head < NH + NKV) {   // q/k: [h][s][d]
        u16* dst; int hh;
        if (head < NH) { dst = qb; hh = head; } else { dst = kb; hh = head - NH; }
        #pragma unroll
        for (int mi = 0; mi < 2; ++mi)
            #pragma unroll
            for (int r = 0; r < 4; ++r) {
                int s = s0 + wr * 32 + mi * 16 + lg * 4 + r;
                #pragma unroll
                for (int ni = 0; ni < 4; ++ni)
                    dst[((size_t)hh * S_LEN + s) * HD + ni * 16 + col] = f2bf(acc[mi][ni][r]);
            }
    } else {                 // v: [h][d][s] transposed, 8B packed stores
        int hh = head - NH - NKV;
        #pragma unroll
        for (int mi = 0; mi < 2; ++mi) {
            int sb = s0 + wr * 32 + mi * 16 + lg * 4;
            #pragma unroll
            for (int ni = 0; ni < 4; ++ni) {
                int d = ni * 16 + col;
                s16x4 pk;
                #pragma unroll
                for (int r = 0; r < 4; ++r) pk[r] = (short)f2bf(acc[mi][ni][r]);
                *(s16x4*)&vb[((size_t)hh * HD + d) * S_LEN + sb] = pk;
            }
        }
    }
}

// ---------------- attention: staged K/V, 2-phase double-buffer, 1 barrier/tile ----------------
// grid (48, 16 heads), 256 thr. Block: 64 q-rows; wave: 16 q-rows. KV tile 64.
__global__ __launch_bounds__(256) void k_attn(
    const u16* __restrict__ qb, const u16* __restrict__ kb, const u16* __restrict__ vb,
    u16* __restrict__ cb)
{
    __shared__ u16 smK[2][64 * 64];
    __shared__ u16 smV[2][64 * 64];      // V^T tile: [d][t]
    __shared__ u16 smP[4 * 16 * 64];     // per-wave P
    const int tid = threadIdx.x;
    const int wv = tid >> 6, ln = tid & 63;
    const int h = blockIdx.y, kvh = h >> 1;
    const int s0 = blockIdx.x * 64;
    const int seg0 = s0 & ~(SEG - 1);
    const int col = ln & 15, lg = ln >> 4;

    bf16x8 qf[2];
    #pragma unroll
    for (int ks = 0; ks < 2; ++ks)
        qf[ks] = *(const bf16x8*)&qb[((size_t)h * S_LEN + s0 + wv * 16 + col) * HD + ks * 32 + lg * 8];

    f32x4 oacc[4] = {};
    float lsum[4] = {0.f, 0.f, 0.f, 0.f};
    u16* myP = &smP[wv * 16 * 64];

    const u16* Kseg = kb + ((size_t)kvh * S_LEN + seg0) * HD;   // [t][d]
    const u16* Vseg = vb + (size_t)kvh * HD * S_LEN + seg0;     // [d][s]

    auto stage = [&](int b, int kt) {
        #pragma unroll
        for (int i = 0; i < 2; ++i) {
            int c = i * 256 + tid; int row = c >> 3, sl = c & 7; int gs = (sl ^ (row & 7)) << 3;
            gld16(&Kseg[(size_t)(kt * 64 + row) * HD + gs], &smK[b][(i * 256 + wv * 64) * 8]);
        }
        #pragma unroll
        for (int i = 0; i < 2; ++i) {
            int c = i * 256 + tid; int row = c >> 3, sl = c & 7; int gs = (sl ^ (row & 7)) << 3;
            gld16(&Vseg[(size_t)row * S_LEN + kt * 64 + gs], &smV[b][(i * 256 + wv * 64) * 8]);
        }
    };

    stage(0, 0);
    __syncthreads();

    for (int kt = 0; kt < SEG / 64; ++kt) {
        const int cur = kt & 1;
        if (kt + 1 < SEG / 64) stage(cur ^ 1, kt + 1);   // prefetch next tile (no wait)

        // QK^T
        f32x4 sacc[4] = {};
        #pragma unroll
        for (int ks = 0; ks < 2; ++ks) {
            bf16x8 kf[4];
            #pragma unroll
            for (int ni = 0; ni < 4; ++ni) {
                int row = ni * 16 + col;
                int sl = (ks * 4 + lg) ^ (row & 7);
                kf[ni] = *(const bf16x8*)&smK[cur][row * 64 + sl * 8];
            }
            #pragma unroll
            for (int ni = 0; ni < 4; ++ni)
                sacc[ni] = __builtin_amdgcn_mfma_f32_16x16x32_bf16(qf[ks], kf[ni], sacc[ni], 0, 0, 0);
        }

        // p = exp2(s); per-lane partial row sums (deferred reduce)
        #pragma unroll
        for (int ni = 0; ni < 4; ++ni)
            #pragma unroll
            for (int r = 0; r < 4; ++r) {
                float p = __builtin_amdgcn_exp2f(sacc[ni][r]);
                sacc[ni][r] = p;
                lsum[r] += p;
            }

        // P -> wave-private LDS (swizzled 128B rows); same-wave, no barrier
        #pragma unroll
        for (int ni = 0; ni < 4; ++ni)
            #pragma unroll
            for (int r = 0; r < 4; ++r) {
                int row = lg * 4 + r;
                int t = ni * 16 + col;
                int b = (t >> 3) ^ (row & 7);
                myP[row * 64 + b * 8 + (t & 7)] = f2bf(sacc[ni][r]);
            }

        // PV
        #pragma unroll
        for (int ks = 0; ks < 2; ++ks) {
            bf16x8 pf, vf[4];
            {
                int row = col;
                int sl = (ks * 4 + lg) ^ (row & 7);
                pf = *(const bf16x8*)&myP[row * 64 + sl * 8];
            }
            #pragma unroll
            for (int ni = 0; ni < 4; ++ni) {
                int row = ni * 16 + col;
                int sl = (ks * 4 + lg) ^ (row & 7);
                vf[ni] = *(const bf16x8*)&smV[cur][row * 64 + sl * 8];
            }
            #pragma unroll
            for (int ni = 0; ni < 4; ++ni)
                oacc[ni] = __builtin_amdgcn_mfma_f32_16x16x32_bf16(pf, vf[ni], oacc[ni], 0, 0, 0);
        }

        __syncthreads();   // drains this wave's prefetch DMA + releases cur for overwrite
    }

    // deferred row-sum reduce (within 16-lane col groups)
    #pragma unroll
    for (int r = 0; r < 4; ++r) {
        float v = lsum[r];
        v += __shfl_xor(v, 1); v += __shfl_xor(v, 2);
        v += __shfl_xor(v, 4); v += __shfl_xor(v, 8);
        lsum[r] = v;
    }

    #pragma unroll
    for (int r = 0; r < 4; ++r) {
        int s = s0 + wv * 16 + lg * 4 + r;
        float inv = 1.f / lsum[r];
        #pragma unroll
        for (int ni = 0; ni < 4; ++ni) {
            int d = ni * 16 + col;
            cb[(size_t)s * E_DIM + h * HD + d] = f2bf(oacc[ni][r] * inv);
        }
    }
}

// ---------------- output projection (64x64 tile, BK=128, f32 out) ----------------
// grid (48, 16), 256 thr. wave 32x32. 8 K-iterations, 16 barriers.
__global__ __launch_bounds__(256) void k_proj(
    const u16* __restrict__ cb, const u16* __restrict__ pwb,
    const float* __restrict__ bias, float* __restrict__ out)
{
    __shared__ u16 smA[64 * 128];    // 16KB
    __shared__ u16 smB[64 * 128];    // 16KB
    const int tid = threadIdx.x;
    const int wv = tid >> 6, ln = tid & 63;
    const int s0 = blockIdx.x * 64, o0 = blockIdx.y * 64;
    const int wr = wv >> 1, wc = wv & 1;
    const int col = ln & 15, lg = ln >> 4;

    f32x4 acc[2][2] = {};

    for (int kt = 0; kt < E_DIM / 128; ++kt) {
        const int k0 = kt * 128;
        #pragma unroll
        for (int i = 0; i < 4; ++i) {       // A: 64x128 = 1024 chunks
            int c = i * 256 + tid; int row = c >> 4, sl = c & 15; int gs = (sl ^ (row & 7)) << 3;
            gld16(&cb[(size_t)(s0 + row) * E_DIM + k0 + gs], &smA[(i * 256 + wv * 64) * 8]);
        }
        #pragma unroll
        for (int i = 0; i < 4; ++i) {       // B: 64x128
            int c = i * 256 + tid; int row = c >> 4, sl = c & 15; int gs = (sl ^ (row & 7)) << 3;
            gld16(&pwb[(size_t)(o0 + row) * E_DIM + k0 + gs], &smB[(i * 256 + wv * 64) * 8]);
        }
        __syncthreads();
        #pragma unroll
        for (int ks = 0; ks < 4; ++ks) {
            bf16x8 a[2], b[2];
            #pragma unroll
            for (int mi = 0; mi < 2; ++mi) {
                int row = wr * 32 + mi * 16 + col;
                int sl = (ks * 4 + lg) ^ (row & 7);
                a[mi] = *(const bf16x8*)&smA[row * 128 + sl * 8];
            }
            #pragma unroll
            for (int ni = 0; ni < 2; ++ni) {
                int row = wc * 32 + ni * 16 + col;
                int sl = (ks * 4 + lg) ^ (row & 7);
                b[ni] = *(const bf16x8*)&smB[row * 128 + sl * 8];
            }
            #pragma unroll
            for (int mi = 0; mi < 2; ++mi)
                #pragma unroll
                for (int ni = 0; ni < 2; ++ni)
                    acc[mi][ni] = __builtin_amdgcn_mfma_f32_16x16x32_bf16(a[mi], b[ni], acc[mi][ni], 0, 0, 0);
        }
        __syncthreads();
    }

    #pragma unroll
    for (int mi = 0; mi < 2; ++mi)
        #pragma unroll
        for (int r = 0; r < 4; ++r) {
            int s = s0 + wr * 32 + mi * 16 + lg * 4 + r;
            #pragma unroll
            for (int ni = 0; ni < 2; ++ni) {
                int o = o0 + wc * 32 + ni * 16 + col;
                out[(size_t)s * E_DIM + o] = acc[mi][ni][r] + bias[o];
            }
        }
}

extern "C" void kernel_launch(void* const* d_in, const int* in_sizes, int n_in,
                              void* d_out, int out_size, void* d_ws, size_t ws_size,
                              hipStream_t stream) {
    const float* x      = (const float*)d_in[0];
    const float* rc     = (const float*)d_in[2];
    const float* rs     = (const float*)d_in[3];
    const float* qkv_w  = (const float*)d_in[4];
    const float* qkv_b  = (const float*)d_in[5];
    const float* proj_w = (const float*)d_in[6];
    const float* proj_b = (const float*)d_in[7];
    float* out = (float*)d_out;

    u16* ws  = (u16*)d_ws;
    u16* xb  = ws;                                  // 3072*1024
    u16* wb  = xb  + (size_t)S_LEN * E_DIM;         // 2048*1024
    u16* pwb = wb  + (size_t)NQKV * E_DIM;          // 1024*1024
    u16* qb  = pwb + (size_t)E_DIM * E_DIM;         // 16*3072*64
    u16* kb  = qb  + (size_t)NH * S_LEN * HD;       // 8*3072*64
    u16* vb  = kb  + (size_t)NKV * S_LEN * HD;      // 8*64*3072 (transposed)
    u16* cb  = vb  + (size_t)NKV * S_LEN * HD;      // 3072*1024

    k_cast<<<1536, 256, 0, stream>>>(x, qkv_w, proj_w, xb, wb, pwb);
    k_qkv <<<dim3(48, 16), 256, 0, stream>>>(xb, wb, qkv_b, rc, rs, qb, kb, vb);
    k_attn<<<dim3(48, 16), 256, 0, stream>>>(qb, kb, vb, cb);
    k_proj<<<dim3(48, 16), 256, 0, stream>>>(cb, pwb, proj_b, out);
}

// Round 13
// 142.109 us; speedup vs baseline: 1.1807x; 1.0301x over previous
//
#include <hip/hip_runtime.h>
#include <cstdint>
#include <cstddef>

#define S_LEN 3072
#define E_DIM 1024
#define NH 16
#define NKV 8
#define HD 64
#define NQKV 2048
#define SEG 1024

typedef __attribute__((ext_vector_type(8))) short bf16x8;
typedef __attribute__((ext_vector_type(4))) short s16x4;
typedef __attribute__((ext_vector_type(4))) float f32x4;
typedef __attribute__((ext_vector_type(4))) float ff4;
typedef unsigned short u16;

// 0.125 * log2(e): folded into Q so attention uses exp2 directly
#define QSCALE 0.1803368801111204f

#if defined(__has_builtin)
#if __has_builtin(__builtin_amdgcn_mfma_f32_16x16x16bf16_1k)
#define HAVE_MFMA16 1
#endif
#endif

__device__ __forceinline__ u16 f2bf(float f) {
    unsigned u = __float_as_uint(f);
    u += 0x7fffu + ((u >> 16) & 1u);
    return (u16)(u >> 16);
}

__device__ __forceinline__ void gld16(const void* g, u16* l) {
    __builtin_amdgcn_global_load_lds(
        (const __attribute__((address_space(1))) unsigned*)g,
        (__attribute__((address_space(3))) unsigned*)l, 16, 0, 0);
}

// ---------------- cast f32 -> bf16 for x, qkv_w, proj_w ----------------
__global__ __launch_bounds__(256) void k_cast(
    const float* __restrict__ x, const float* __restrict__ w, const float* __restrict__ pw,
    u16* __restrict__ xb, u16* __restrict__ wb, u16* __restrict__ pwb)
{
    const int n1 = (S_LEN * E_DIM) / 4, n2 = (NQKV * E_DIM) / 4, n3 = (E_DIM * E_DIM) / 4;
    const int total = n1 + n2 + n3;
    for (int i = blockIdx.x * 256 + threadIdx.x; i < total; i += gridDim.x * 256) {
        const float* s; u16* d; int j;
        if (i < n1)           { s = x;  d = xb;  j = i; }
        else if (i < n1 + n2) { s = w;  d = wb;  j = i - n1; }
        else                  { s = pw; d = pwb; j = i - n1 - n2; }
        ff4 v = *(const ff4*)&s[(size_t)j * 4];
        unsigned lo = (unsigned)f2bf(v.x) | ((unsigned)f2bf(v.y) << 16);
        unsigned hi = (unsigned)f2bf(v.z) | ((unsigned)f2bf(v.w) << 16);
        uint2 pk; pk.x = lo; pk.y = hi;
        *(uint2*)&d[(size_t)j * 4] = pk;
    }
}

// ---------------- QKV GEMM (64x128, BK=64, 768 blocks) + bias + RoPE + scatter ------
// grid (48, 16), 256 thr. wave: 32(M) x 64(N).
__global__ __launch_bounds__(256) void k_qkv(
    const u16* __restrict__ xb, const u16* __restrict__ wb,
    const float* __restrict__ bias, const float* __restrict__ rc, const float* __restrict__ rs,
    u16* __restrict__ qb, u16* __restrict__ kb, u16* __restrict__ vb)
{
    __shared__ u16 smA[64 * 64];
    __shared__ u16 smB[128 * 64];
    const int tid = threadIdx.x;
    const int wv = tid >> 6, ln = tid & 63;
    const int s0 = blockIdx.x * 64;
    const int o0 = blockIdx.y * 128;
    const int wr = wv >> 1, wc = wv & 1;
    const int col = ln & 15, lg = ln >> 4;

    f32x4 acc[2][4] = {};

    for (int kt = 0; kt < E_DIM / 64; ++kt) {
        const int k0 = kt * 64;
        #pragma unroll
        for (int i = 0; i < 2; ++i) {       // A: 64x64 = 512 chunks
            int c = i * 256 + tid;
            int row = c >> 3, sl = c & 7;
            int gs = (sl ^ (row & 7)) << 3;
            gld16(&xb[(size_t)(s0 + row) * E_DIM + k0 + gs], &smA[(i * 256 + wv * 64) * 8]);
        }
        #pragma unroll
        for (int i = 0; i < 4; ++i) {       // B: 128x64 = 1024 chunks
            int c = i * 256 + tid;
            int row = c >> 3, sl = c & 7;
            int gs = (sl ^ (row & 7)) << 3;
            gld16(&wb[(size_t)(o0 + row) * E_DIM + k0 + gs], &smB[(i * 256 + wv * 64) * 8]);
        }
        __syncthreads();
        #pragma unroll
        for (int ks = 0; ks < 2; ++ks) {
            bf16x8 a[2], b[4];
            #pragma unroll
            for (int mi = 0; mi < 2; ++mi) {
                int row = wr * 32 + mi * 16 + col;
                int sl = (ks * 4 + lg) ^ (row & 7);
                a[mi] = *(const bf16x8*)&smA[row * 64 + sl * 8];
            }
            #pragma unroll
            for (int ni = 0; ni < 4; ++ni) {
                int row = wc * 64 + ni * 16 + col;
                int sl = (ks * 4 + lg) ^ (row & 7);
                b[ni] = *(const bf16x8*)&smB[row * 64 + sl * 8];
            }
            #pragma unroll
            for (int mi = 0; mi < 2; ++mi)
                #pragma unroll
                for (int ni = 0; ni < 4; ++ni)
                    acc[mi][ni] = __builtin_amdgcn_mfma_f32_16x16x32_bf16(a[mi], b[ni], acc[mi][ni], 0, 0, 0);
        }
        __syncthreads();
    }

    const int ocol0 = o0 + wc * 64;      // wave covers exactly one head
    const int head = ocol0 >> 6;
    #pragma unroll
    for (int ni = 0; ni < 4; ++ni) {
        float bv = bias[ocol0 + ni * 16 + col];
        #pragma unroll
        for (int mi = 0; mi < 2; ++mi)
            #pragma unroll
            for (int r = 0; r < 4; ++r)
                acc[mi][ni][r] += bv;
    }
    if (head < NH + NKV) {   // RoPE on q and k heads
        #pragma unroll
        for (int mi = 0; mi < 2; ++mi)
            #pragma unroll
            for (int r = 0; r < 4; ++r) {
                int s = s0 + wr * 32 + mi * 16 + lg * 4 + r;
                #pragma unroll
                for (int ni = 0; ni < 2; ++ni) {
                    int d2 = ni * 16 + col;
                    float c = rc[s * 32 + d2], sn = rs[s * 32 + d2];
                    float t1 = acc[mi][ni][r], t2 = acc[mi][ni + 2][r];
                    acc[mi][ni][r]     = t1 * c - t2 * sn;
                    acc[mi][ni + 2][r] = t1 * sn + t2 * c;
                }
            }
    }
    if (head < NH) {         // fold 0.125*log2e into Q (attention uses exp2)
        #pragma unroll
        for (int mi = 0; mi < 2; ++mi)
            #pragma unroll
            for (int ni = 0; ni < 4; ++ni)
                #pragma unroll
                for (int r = 0; r < 4; ++r)
                    acc[mi][ni][r] *= QSCALE;
    }
    if (head < NH + NKV) {   // q/k: [h][s][d]
        u16* dst; int hh;
        if (head < NH) { dst = qb; hh = head; } else { dst = kb; hh = head - NH; }
        #pragma unroll
        for (int mi = 0; mi < 2; ++mi)
            #pragma unroll
            for (int r = 0; r < 4; ++r) {
                int s = s0 + wr * 32 + mi * 16 + lg * 4 + r;
                #pragma unroll
                for (int ni = 0; ni < 4; ++ni)
                    dst[((size_t)hh * S_LEN + s) * HD + ni * 16 + col] = f2bf(acc[mi][ni][r]);
            }
    } else {                 // v: [h][d][s] transposed, 8B packed stores
        int hh = head - NH - NKV;
        #pragma unroll
        for (int mi = 0; mi < 2; ++mi) {
            int sb = s0 + wr * 32 + mi * 16 + lg * 4;
            #pragma unroll
            for (int ni = 0; ni < 4; ++ni) {
                int d = ni * 16 + col;
                s16x4 pk;
                #pragma unroll
                for (int r = 0; r < 4; ++r) pk[r] = (short)f2bf(acc[mi][ni][r]);
                *(s16x4*)&vb[((size_t)hh * HD + d) * S_LEN + sb] = pk;
            }
        }
    }
}

// ---------------- attention ----------------
// grid (48, 16 heads), 256 thr. Block: 64 q-rows; wave: 16 q-rows. KV tile 64.
// MFMA16 path: swapped QK^T (S^T in regs) -> P is lane-local in exactly the
// mfma_16x16x16 A-fragment layout -> no P LDS round-trip, no f2bf scatter.
__global__ __launch_bounds__(256) void k_attn(
    const u16* __restrict__ qb, const u16* __restrict__ kb, const u16* __restrict__ vb,
    u16* __restrict__ cb)
{
    __shared__ u16 smK[2][64 * 64];
    __shared__ u16 smV[2][64 * 64];      // V^T tile: [d][t]
#ifndef HAVE_MFMA16
    __shared__ u16 smP[4 * 16 * 64];     // fallback per-wave P
#endif
    const int tid = threadIdx.x;
    const int wv = tid >> 6, ln = tid & 63;
    const int h = blockIdx.y, kvh = h >> 1;
    const int s0 = blockIdx.x * 64;
    const int seg0 = s0 & ~(SEG - 1);
    const int col = ln & 15, lg = ln >> 4;

    bf16x8 qf[2];
    #pragma unroll
    for (int ks = 0; ks < 2; ++ks)
        qf[ks] = *(const bf16x8*)&qb[((size_t)h * S_LEN + s0 + wv * 16 + col) * HD + ks * 32 + lg * 8];

    f32x4 oacc[4] = {};

    const u16* Kseg = kb + ((size_t)kvh * S_LEN + seg0) * HD;   // [t][d]
    const u16* Vseg = vb + (size_t)kvh * HD * S_LEN + seg0;     // [d][s]

    auto stage = [&](int b, int kt) {
        #pragma unroll
        for (int i = 0; i < 2; ++i) {
            int c = i * 256 + tid; int row = c >> 3, sl = c & 7; int gs = (sl ^ (row & 7)) << 3;
            gld16(&Kseg[(size_t)(kt * 64 + row) * HD + gs], &smK[b][(i * 256 + wv * 64) * 8]);
        }
        #pragma unroll
        for (int i = 0; i < 2; ++i) {
            int c = i * 256 + tid; int row = c >> 3, sl = c & 7; int gs = (sl ^ (row & 7)) << 3;
            gld16(&Vseg[(size_t)row * S_LEN + kt * 64 + gs], &smV[b][(i * 256 + wv * 64) * 8]);
        }
    };

    stage(0, 0);
    __syncthreads();

#ifdef HAVE_MFMA16
    float lsum = 0.f;

    for (int kt = 0; kt < SEG / 64; ++kt) {
        const int cur = kt & 1;
        if (kt + 1 < SEG / 64) stage(cur ^ 1, kt + 1);   // prefetch next tile (no wait)

        // QK^T swapped: sacc = S^T. Lane holds q-row s=col, t = ni*16 + lg*4 + r.
        f32x4 sacc[4] = {};
        #pragma unroll
        for (int ks = 0; ks < 2; ++ks) {
            bf16x8 kf[4];
            #pragma unroll
            for (int ni = 0; ni < 4; ++ni) {
                int row = ni * 16 + col;
                int sl = (ks * 4 + lg) ^ (row & 7);
                kf[ni] = *(const bf16x8*)&smK[cur][row * 64 + sl * 8];
            }
            #pragma unroll
            for (int ni = 0; ni < 4; ++ni)
                sacc[ni] = __builtin_amdgcn_mfma_f32_16x16x32_bf16(kf[ni], qf[ks], sacc[ni], 0, 0, 0);
        }

        // p = exp2(s); pack to bf16 pairs in-register (A-frag of mfma 16x16x16)
        s16x4 pk4[4];
        #pragma unroll
        for (int ni = 0; ni < 4; ++ni) {
            float p0 = __builtin_amdgcn_exp2f(sacc[ni][0]);
            float p1 = __builtin_amdgcn_exp2f(sacc[ni][1]);
            float p2 = __builtin_amdgcn_exp2f(sacc[ni][2]);
            float p3 = __builtin_amdgcn_exp2f(sacc[ni][3]);
            lsum += (p0 + p1) + (p2 + p3);
            unsigned lo, hi;
            asm("v_cvt_pk_bf16_f32 %0, %1, %2" : "=v"(lo) : "v"(p0), "v"(p1));
            asm("v_cvt_pk_bf16_f32 %0, %1, %2" : "=v"(hi) : "v"(p2), "v"(p3));
            union { unsigned u[2]; s16x4 v; } pu;
            pu.u[0] = lo; pu.u[1] = hi;
            pk4[ni] = pu.v;
        }

        // PV: O[s][d] += sum_nk P_frag[nk] x V_frag[nk][d], K=16 MFMAs
        #pragma unroll
        for (int nk = 0; nk < 4; ++nk) {
            #pragma unroll
            for (int nd = 0; nd < 4; ++nd) {
                int row = nd * 16 + col;                     // d index
                int sl = (2 * nk + (lg >> 1)) ^ (row & 7);   // t = nk*16 + lg*4 + j
                s16x4 vf4 = *(const s16x4*)&smV[cur][row * 64 + sl * 8 + (lg & 1) * 4];
                oacc[nd] = __builtin_amdgcn_mfma_f32_16x16x16bf16_1k(pk4[nk], vf4, oacc[nd], 0, 0, 0);
            }
        }

        __syncthreads();   // drains prefetch DMA + releases cur for overwrite
    }

    // lanes {col, col+16, col+32, col+48} hold partials of q-row = col
    lsum += __shfl_xor(lsum, 16);
    lsum += __shfl_xor(lsum, 32);

    #pragma unroll
    for (int r = 0; r < 4; ++r) {
        float ls = __shfl(lsum, lg * 4 + r);   // lane (lg*4+r) has col == lg*4+r
        int s = s0 + wv * 16 + lg * 4 + r;
        float inv = 1.f / ls;
        #pragma unroll
        for (int nd = 0; nd < 4; ++nd)
            cb[(size_t)s * E_DIM + h * HD + nd * 16 + col] = f2bf(oacc[nd][r] * inv);
    }

#else   // fallback: R6 path (P through wave-private LDS)
    float lsum4[4] = {0.f, 0.f, 0.f, 0.f};
    u16* myP = &smP[wv * 16 * 64];

    for (int kt = 0; kt < SEG / 64; ++kt) {
        const int cur = kt & 1;
        if (kt + 1 < SEG / 64) stage(cur ^ 1, kt + 1);

        f32x4 sacc[4] = {};
        #pragma unroll
        for (int ks = 0; ks < 2; ++ks) {
            bf16x8 kf[4];
            #pragma unroll
            for (int ni = 0; ni < 4; ++ni) {
                int row = ni * 16 + col;
                int sl = (ks * 4 + lg) ^ (row & 7);
                kf[ni] = *(const bf16x8*)&smK[cur][row * 64 + sl * 8];
            }
            #pragma unroll
            for (int ni = 0; ni < 4; ++ni)
                sacc[ni] = __builtin_amdgcn_mfma_f32_16x16x32_bf16(qf[ks], kf[ni], sacc[ni], 0, 0, 0);
        }
        #pragma unroll
        for (int ni = 0; ni < 4; ++ni)
            #pragma unroll
            for (int r = 0; r < 4; ++r) {
                float p = __builtin_amdgcn_exp2f(sacc[ni][r]);
                sacc[ni][r] = p;
                lsum4[r] += p;
            }
        #pragma unroll
        for (int ni = 0; ni < 4; ++ni)
            #pragma unroll
            for (int r = 0; r < 4; ++r) {
                int row = lg * 4 + r;
                int t = ni * 16 + col;
                int b = (t >> 3) ^ (row & 7);
                myP[row * 64 + b * 8 + (t & 7)] = f2bf(sacc[ni][r]);
            }
        #pragma unroll
        for (int ks = 0; ks < 2; ++ks) {
            bf16x8 pf, vf[4];
            {
                int row = col;
                int sl = (ks * 4 + lg) ^ (row & 7);
                pf = *(const bf16x8*)&myP[row * 64 + sl * 8];
            }
            #pragma unroll
            for (int ni = 0; ni < 4; ++ni) {
                int row = ni * 16 + col;
                int sl = (ks * 4 + lg) ^ (row & 7);
                vf[ni] = *(const bf16x8*)&smV[cur][row * 64 + sl * 8];
            }
            #pragma unroll
            for (int ni = 0; ni < 4; ++ni)
                oacc[ni] = __builtin_amdgcn_mfma_f32_16x16x32_bf16(pf, vf[ni], oacc[ni], 0, 0, 0);
        }
        __syncthreads();
    }

    #pragma unroll
    for (int r = 0; r < 4; ++r) {
        float v = lsum4[r];
        v += __shfl_xor(v, 1); v += __shfl_xor(v, 2);
        v += __shfl_xor(v, 4); v += __shfl_xor(v, 8);
        lsum4[r] = v;
    }
    #pragma unroll
    for (int r = 0; r < 4; ++r) {
        int s = s0 + wv * 16 + lg * 4 + r;
        float inv = 1.f / lsum4[r];
        #pragma unroll
        for (int ni = 0; ni < 4; ++ni)
            cb[(size_t)s * E_DIM + h * HD + ni * 16 + col] = f2bf(oacc[ni][r] * inv);
    }
#endif
}

// ---------------- output projection (64x64, BK=64, 768 blocks, f32 out) -------------
// grid (48, 16), 256 thr. wave 32x32.
__global__ __launch_bounds__(256) void k_proj(
    const u16* __restrict__ cb, const u16* __restrict__ pwb,
    const float* __restrict__ bias, float* __restrict__ out)
{
    __shared__ u16 smA[64 * 64];
    __shared__ u16 smB[64 * 64];
    const int tid = threadIdx.x;
    const int wv = tid >> 6, ln = tid & 63;
    const int s0 = blockIdx.x * 64, o0 = blockIdx.y * 64;
    const int wr = wv >> 1, wc = wv & 1;
    const int col = ln & 15, lg = ln >> 4;

    f32x4 acc[2][2] = {};

    for (int kt = 0; kt < E_DIM / 64; ++kt) {
        const int k0 = kt * 64;
        #pragma unroll
        for (int i = 0; i < 2; ++i) {
            int c = i * 256 + tid; int row = c >> 3, sl = c & 7; int gs = (sl ^ (row & 7)) << 3;
            gld16(&cb[(size_t)(s0 + row) * E_DIM + k0 + gs], &smA[(i * 256 + wv * 64) * 8]);
        }
        #pragma unroll
        for (int i = 0; i < 2; ++i) {
            int c = i * 256 + tid; int row = c >> 3, sl = c & 7; int gs = (sl ^ (row & 7)) << 3;
            gld16(&pwb[(size_t)(o0 + row) * E_DIM + k0 + gs], &smB[(i * 256 + wv * 64) * 8]);
        }
        __syncthreads();
        #pragma unroll
        for (int ks = 0; ks < 2; ++ks) {
            bf16x8 a[2], b[2];
            #pragma unroll
            for (int mi = 0; mi < 2; ++mi) {
                int row = wr * 32 + mi * 16 + col;
                int sl = (ks * 4 + lg) ^ (row & 7);
                a[mi] = *(const bf16x8*)&smA[row * 64 + sl * 8];
            }
            #pragma unroll
            for (int ni = 0; ni < 2; ++ni) {
                int row = wc * 32 + ni * 16 + col;
                int sl = (ks * 4 + lg) ^ (row & 7);
                b[ni] = *(const bf16x8*)&smB[row * 64 + sl * 8];
            }
            #pragma unroll
            for (int mi = 0; mi < 2; ++mi)
                #pragma unroll
                for (int ni = 0; ni < 2; ++ni)
                    acc[mi][ni] = __builtin_amdgcn_mfma_f32_16x16x32_bf16(a[mi], b[ni], acc[mi][ni], 0, 0, 0);
        }
        __syncthreads();
    }

    #pragma unroll
    for (int mi = 0; mi < 2; ++mi)
        #pragma unroll
        for (int r = 0; r < 4; ++r) {
            int s = s0 + wr * 32 + mi * 16 + lg * 4 + r;
            #pragma unroll
            for (int ni = 0; ni < 2; ++ni) {
                int o = o0 + wc * 32 + ni * 16 + col;
                out[(size_t)s * E_DIM + o] = acc[mi][ni][r] + bias[o];
            }
        }
}

extern "C" void kernel_launch(void* const* d_in, const int* in_sizes, int n_in,
                              void* d_out, int out_size, void* d_ws, size_t ws_size,
                              hipStream_t stream) {
    const float* x      = (const float*)d_in[0];
    const float* rc     = (const float*)d_in[2];
    const float* rs     = (const float*)d_in[3];
    const float* qkv_w  = (const float*)d_in[4];
    const float* qkv_b  = (const float*)d_in[5];
    const float* proj_w = (const float*)d_in[6];
    const float* proj_b = (const float*)d_in[7];
    float* out = (float*)d_out;

    u16* ws  = (u16*)d_ws;
    u16* xb  = ws;                                  // 3072*1024
    u16* wb  = xb  + (size_t)S_LEN * E_DIM;         // 2048*1024
    u16* pwb = wb  + (size_t)NQKV * E_DIM;          // 1024*1024
    u16* qb  = pwb + (size_t)E_DIM * E_DIM;         // 16*3072*64
    u16* kb  = qb  + (size_t)NH * S_LEN * HD;       // 8*3072*64
    u16* vb  = kb  + (size_t)NKV * S_LEN * HD;      // 8*64*3072 (transposed)
    u16* cb  = vb  + (size_t)NKV * S_LEN * HD;      // 3072*1024

    k_cast<<<1536, 256, 0, stream>>>(x, qkv_w, proj_w, xb, wb, pwb);
    k_qkv <<<dim3(48, 16), 256, 0, stream>>>(xb, wb, qkv_b, rc, rs, qb, kb, vb);
    k_attn<<<dim3(48, 16), 256, 0, stream>>>(qb, kb, vb, cb);
    k_proj<<<dim3(48, 16), 256, 0, stream>>>(cb, pwb, proj_b, out);
}